// Round 1
// baseline (496.570 us; speedup 1.0000x reference)
//
#include <hip/hip_runtime.h>

// Point-in-polygon mask, P=2^21 polygons x E=8 vertices, N = 16,777,216 points.
//
// Segments are contiguous aligned blocks of 8, so the reference's global
// cumsum / scatter-diff / second cumsum collapse to:
//   count_i = sum of is_intersect over polygon i's 8 points
//   out[k]  = (count_{k/8} == 1)
// Pure elementwise + one 2-lane shuffle reduce. No scan, no atomics, no LDS.
//
// s1, vertices_range, vertices_indices are never read (dead inputs).
// __fmul_rn/__fadd_rn keep x_cross bit-identical to the reference (no FMA
// contraction), so the >= comparison can never flip.
//
// This revision (R1): 4 points per thread so ALL streams are 16 B/lane
// (points/s2: 2x float4 each; miny/maxy/xchk: 1x float4 each; out: 1x int4),
// plus a capped-grid grid-stride loop (2048 blocks x 256 thr x 8 iters covers
// n4 = 4,194,304 exactly -> no tail, no divergence).
//
// OUTPUT DTYPE: harness reads d_out as int32 -> store integer 0/1.

__global__ __launch_bounds__(256) void pip_mask_kernel(
    const float4* __restrict__ points4,  // 2 points per float4 (x0,y0,x1,y1)
    const float4* __restrict__ s2_4,     // same layout as points
    const float4* __restrict__ miny4,    // 4 points per float4
    const float4* __restrict__ maxy4,    // 4 points per float4
    const float4* __restrict__ xchk4,    // 4 points per float4
    int4*         __restrict__ out4,     // 4 int32 flags per thread-iter
    int n4)                              // = N/4
{
    const int stride = gridDim.x * blockDim.x;
    for (int i = blockIdx.x * blockDim.x + threadIdx.x; i < n4; i += stride) {
        // Group i covers points 4i..4i+3. Polygon = 8 points = groups {2j,2j+1},
        // i.e. lane pairs (tid, tid^1): i parity == tid parity because block
        // size and grid stride are even.
        float4 p0 = points4[2 * i];
        float4 p1 = points4[2 * i + 1];
        float4 s0 = s2_4[2 * i];
        float4 s1 = s2_4[2 * i + 1];
        float4 mn = miny4[i];
        float4 mx = maxy4[i];
        float4 xc = xchk4[i];

        int c = 0;
        {   // point 4i+0: (px,py) = (p0.x, p0.y)
            bool y_ok = (p0.y >= mn.x) && (p0.y < mx.x);
            float xcr = __fadd_rn(s0.x, __fmul_rn(p0.y - s0.y, xc.x));
            c += (y_ok && (xcr >= p0.x)) ? 1 : 0;
        }
        {   // point 4i+1: (px,py) = (p0.z, p0.w)
            bool y_ok = (p0.w >= mn.y) && (p0.w < mx.y);
            float xcr = __fadd_rn(s0.z, __fmul_rn(p0.w - s0.w, xc.y));
            c += (y_ok && (xcr >= p0.z)) ? 1 : 0;
        }
        {   // point 4i+2: (px,py) = (p1.x, p1.y)
            bool y_ok = (p1.y >= mn.z) && (p1.y < mx.z);
            float xcr = __fadd_rn(s1.x, __fmul_rn(p1.y - s1.y, xc.z));
            c += (y_ok && (xcr >= p1.x)) ? 1 : 0;
        }
        {   // point 4i+3: (px,py) = (p1.z, p1.w)
            bool y_ok = (p1.w >= mn.w) && (p1.w < mx.w);
            float xcr = __fadd_rn(s1.z, __fmul_rn(p1.w - s1.w, xc.w));
            c += (y_ok && (xcr >= p1.z)) ? 1 : 0;
        }

        // Polygon sum: this thread's 4 points + partner lane's 4 points.
        c += __shfl_xor(c, 1);

        int w = (c == 1) ? 1 : 0;
        out4[i] = make_int4(w, w, w, w);
    }
}

extern "C" void kernel_launch(void* const* d_in, const int* in_sizes, int n_in,
                              void* d_out, int out_size, void* d_ws, size_t ws_size,
                              hipStream_t stream) {
    const float4* points4 = (const float4*)d_in[0];  // points (N,2) f32
    // d_in[1] = s1 — unused by the reference computation
    const float4* s2_4    = (const float4*)d_in[2];  // s2 (N,2) f32
    // d_in[3] = vertices_range, d_in[4] = vertices_indices — statically known
    const float4* miny4   = (const float4*)d_in[5];
    const float4* maxy4   = (const float4*)d_in[6];
    const float4* xchk4   = (const float4*)d_in[7];
    int4* out4 = (int4*)d_out;

    const int n_points = in_sizes[0] / 2;   // N
    const int n4 = n_points / 4;            // 4 points per thread-iteration

    const int block = 256;
    int grid = (n4 + block - 1) / block;
    if (grid > 2048) grid = 2048;           // grid-stride, G11 capped-grid pattern
    pip_mask_kernel<<<grid, block, 0, stream>>>(points4, s2_4, miny4, maxy4,
                                                xchk4, out4, n4);
}

// Round 3
// 488.688 us; speedup vs baseline: 1.0161x; 1.0161x over previous
//
#include <hip/hip_runtime.h>

// Point-in-polygon mask, P=2^21 polygons x E=8 vertices, N = 16,777,216 points.
//
// Segments are contiguous aligned blocks of 8, so the reference's global
// cumsum / scatter-diff / second cumsum collapse to:
//   count_i = sum of is_intersect over polygon i's 8 points
//   out[k]  = (count_{k/8} == 1)
// Pure elementwise + 4-lane shuffle reduce. No scan, no atomics, no LDS.
//
// s1, vertices_range, vertices_indices are never read (dead inputs).
// __fmul_rn/__fadd_rn keep x_cross bit-identical to the reference (no FMA
// contraction), so the >= comparison can never flip.
//
// R2/R3 (R2 bench was an infra failure; identical resubmit): R1 rocprof showed
// kernel dispatch ~152 us inside ~497 us bench (fixed re-poison overhead).
// R1's paired loads points4[2i], points4[2i+1] made every load instruction
// lane-stride 32 B (half-efficient transactions). This version restores
// unit-stride-per-instruction everywhere:
//   each thread-step owns ONE float4 index i (2 points):
//     points4[i] 16 B | s2_4[i] 16 B | miny2/maxy2/xchk2[i] 8 B | out2[i] 8 B
//   polygon = 4 consecutive float4 indices = 4 consecutive lanes
// Grid-stride with 4096 blocks (1,048,576 threads, 8 steps, exact cover),
// unrolled x2 with all loads issued before compute (MLP; ~40 VGPRs).
//
// OUTPUT DTYPE: harness reads d_out as int32 -> store integer 0/1.

__device__ __forceinline__ int pair_count(float4 p, float4 s, float2 mn,
                                          float2 mx, float2 xc) {
    int c = 0;
    {   // even point: (px,py) = (p.x, p.y)
        bool y_ok = (p.y >= mn.x) && (p.y < mx.x);
        float xcr = __fadd_rn(s.x, __fmul_rn(p.y - s.y, xc.x));
        c += (y_ok && (xcr >= p.x)) ? 1 : 0;
    }
    {   // odd point: (px,py) = (p.z, p.w)
        bool y_ok = (p.w >= mn.y) && (p.w < mx.y);
        float xcr = __fadd_rn(s.z, __fmul_rn(p.w - s.w, xc.y));
        c += (y_ok && (xcr >= p.z)) ? 1 : 0;
    }
    return c;
}

__global__ __launch_bounds__(256) void pip_mask_kernel(
    const float4* __restrict__ points4,  // N/2: (x0,y0,x1,y1) = 2 points
    const float4* __restrict__ s2_4,     // N/2: same layout
    const float2* __restrict__ miny2,    // N/2: caches, 2 points per float2
    const float2* __restrict__ maxy2,    // N/2
    const float2* __restrict__ xchk2,    // N/2
    int2*         __restrict__ out2,     // N/2: two int32 flags
    int n2)                              // = N/2
{
    const int tt = gridDim.x * blockDim.x;  // total threads (multiple of 4)
    int i0 = blockIdx.x * blockDim.x + threadIdx.x;

    // Unrolled x2: issue all 10 loads before any compute (widen MLP).
    for (; i0 + tt < n2; i0 += 2 * tt) {
        const int i1 = i0 + tt;
        float4 pA = points4[i0];
        float4 sA = s2_4[i0];
        float2 mnA = miny2[i0];
        float2 mxA = maxy2[i0];
        float2 xcA = xchk2[i0];
        float4 pB = points4[i1];
        float4 sB = s2_4[i1];
        float2 mnB = miny2[i1];
        float2 mxB = maxy2[i1];
        float2 xcB = xchk2[i1];

        int cA = pair_count(pA, sA, mnA, mxA, xcA);
        int cB = pair_count(pB, sB, mnB, mxB, xcB);

        // Polygon = 8 points = 4 consecutive float4 indices = 4 consecutive
        // lanes (tt % 4 == 0, so i % 4 == lane % 4; groups are aligned).
        cA += __shfl_xor(cA, 1);
        cA += __shfl_xor(cA, 2);
        cB += __shfl_xor(cB, 1);
        cB += __shfl_xor(cB, 2);

        int wA = (cA == 1) ? 1 : 0;
        int wB = (cB == 1) ? 1 : 0;
        out2[i0] = make_int2(wA, wA);
        out2[i1] = make_int2(wB, wB);
    }
    // Remainder (not taken for N=2^24 with 4096x256 grid, kept for safety;
    // n2 % 4 == 0 so 4-lane groups drop out together and shuffles stay valid).
    for (; i0 < n2; i0 += tt) {
        float4 p = points4[i0];
        float4 s = s2_4[i0];
        float2 mn = miny2[i0];
        float2 mx = maxy2[i0];
        float2 xc = xchk2[i0];
        int c = pair_count(p, s, mn, mx, xc);
        c += __shfl_xor(c, 1);
        c += __shfl_xor(c, 2);
        int w = (c == 1) ? 1 : 0;
        out2[i0] = make_int2(w, w);
    }
}

extern "C" void kernel_launch(void* const* d_in, const int* in_sizes, int n_in,
                              void* d_out, int out_size, void* d_ws, size_t ws_size,
                              hipStream_t stream) {
    const float4* points4 = (const float4*)d_in[0];  // points (N,2) f32
    // d_in[1] = s1 — unused by the reference computation
    const float4* s2_4    = (const float4*)d_in[2];  // s2 (N,2) f32
    // d_in[3] = vertices_range, d_in[4] = vertices_indices — statically known
    const float2* miny2   = (const float2*)d_in[5];
    const float2* maxy2   = (const float2*)d_in[6];
    const float2* xchk2   = (const float2*)d_in[7];
    int2* out2 = (int2*)d_out;

    const int n_points = in_sizes[0] / 2;   // N
    const int n2 = n_points / 2;            // one float4-index (2 points) per step

    const int block = 256;
    int grid = (n2 + block - 1) / block;
    if (grid > 4096) grid = 4096;           // 8 steps/thread, exact cover at N=2^24
    pip_mask_kernel<<<grid, block, 0, stream>>>(points4, s2_4, miny2, maxy2,
                                                xchk2, out2, n2);
}

// Round 4
// 483.409 us; speedup vs baseline: 1.0272x; 1.0109x over previous
//
#include <hip/hip_runtime.h>

// Point-in-polygon mask, P=2^21 polygons x E=8 vertices, N = 16,777,216 points.
//
// Segments are contiguous aligned blocks of 8, so the reference's global
// cumsum / scatter-diff / second cumsum collapse to:
//   count_i = sum of is_intersect over polygon i's 8 points
//   out[k]  = (count_{k/8} == 1)
//
// s1, vertices_range, vertices_indices are never read (dead inputs).
// __fmul_rn/__fadd_rn keep x_cross bit-identical to the reference (no FMA
// contraction), so the >= comparison can never flip.
//
// R4: ONE POLYGON PER THREAD. R1-R3 rocprof showed a latency-bound regime:
// VALUBusy ~3.7%, effective rate 3.35 TB/s << 6.3 achievable, traffic ideal,
// VGPR=24 (compiler drained each small load batch -> ~5 loads in flight).
// This version gives each thread 14 independent float4 loads (224 B in
// flight/lane), zero cross-lane ops (polygon sum is intra-thread -> no
// ds_swizzle), 2x int4 stores, one-shot grid (8192 blocks, no loop).
//
// OUTPUT DTYPE: harness reads d_out as int32 -> store integer 0/1.

__device__ __forceinline__ int pair_count(float px0, float py0, float px1, float py1,
                                          float s2x0, float s2y0, float s2x1, float s2y1,
                                          float mn0, float mn1, float mx0, float mx1,
                                          float xc0, float xc1) {
    int c = 0;
    {
        bool y_ok = (py0 >= mn0) && (py0 < mx0);
        float xcr = __fadd_rn(s2x0, __fmul_rn(py0 - s2y0, xc0));
        c += (y_ok && (xcr >= px0)) ? 1 : 0;
    }
    {
        bool y_ok = (py1 >= mn1) && (py1 < mx1);
        float xcr = __fadd_rn(s2x1, __fmul_rn(py1 - s2y1, xc1));
        c += (y_ok && (xcr >= px1)) ? 1 : 0;
    }
    return c;
}

__global__ __launch_bounds__(256) void pip_mask_kernel(
    const float4* __restrict__ points4,  // N/2: (x0,y0,x1,y1) = 2 points each
    const float4* __restrict__ s2_4,     // N/2: same layout
    const float4* __restrict__ miny4,    // N/4: 4 points per float4
    const float4* __restrict__ maxy4,    // N/4
    const float4* __restrict__ xchk4,    // N/4
    int4*         __restrict__ out4,     // N/4: 4 int32 flags each
    int npoly)                           // = N/8 = 2^21
{
    int t = blockIdx.x * blockDim.x + threadIdx.x;
    if (t >= npoly) return;

    // Polygon t owns points 8t..8t+7:
    //   points4 / s2_4 indices 4t..4t+3   (2 points per float4)
    //   miny4/maxy4/xchk4 indices 2t,2t+1 (4 points per float4)
    //   out4 indices 2t,2t+1
    const int b4 = 4 * t;
    const int b2 = 2 * t;

    // Issue all 14 loads up front — independent, schedulable as one batch.
    float4 p0 = points4[b4 + 0];
    float4 p1 = points4[b4 + 1];
    float4 p2 = points4[b4 + 2];
    float4 p3 = points4[b4 + 3];
    float4 s0 = s2_4[b4 + 0];
    float4 s1 = s2_4[b4 + 1];
    float4 s2 = s2_4[b4 + 2];
    float4 s3 = s2_4[b4 + 3];
    float4 mnA = miny4[b2 + 0];
    float4 mnB = miny4[b2 + 1];
    float4 mxA = maxy4[b2 + 0];
    float4 mxB = maxy4[b2 + 1];
    float4 xcA = xchk4[b2 + 0];
    float4 xcB = xchk4[b2 + 1];

    int c = 0;
    // points 0,1
    c += pair_count(p0.x, p0.y, p0.z, p0.w, s0.x, s0.y, s0.z, s0.w,
                    mnA.x, mnA.y, mxA.x, mxA.y, xcA.x, xcA.y);
    // points 2,3
    c += pair_count(p1.x, p1.y, p1.z, p1.w, s1.x, s1.y, s1.z, s1.w,
                    mnA.z, mnA.w, mxA.z, mxA.w, xcA.z, xcA.w);
    // points 4,5
    c += pair_count(p2.x, p2.y, p2.z, p2.w, s2.x, s2.y, s2.z, s2.w,
                    mnB.x, mnB.y, mxB.x, mxB.y, xcB.x, xcB.y);
    // points 6,7
    c += pair_count(p3.x, p3.y, p3.z, p3.w, s3.x, s3.y, s3.z, s3.w,
                    mnB.z, mnB.w, mxB.z, mxB.w, xcB.z, xcB.w);

    int w = (c == 1) ? 1 : 0;
    int4 ww = make_int4(w, w, w, w);
    out4[b2 + 0] = ww;
    out4[b2 + 1] = ww;
}

extern "C" void kernel_launch(void* const* d_in, const int* in_sizes, int n_in,
                              void* d_out, int out_size, void* d_ws, size_t ws_size,
                              hipStream_t stream) {
    const float4* points4 = (const float4*)d_in[0];  // points (N,2) f32
    // d_in[1] = s1 — unused by the reference computation
    const float4* s2_4    = (const float4*)d_in[2];  // s2 (N,2) f32
    // d_in[3] = vertices_range, d_in[4] = vertices_indices — statically known
    const float4* miny4   = (const float4*)d_in[5];
    const float4* maxy4   = (const float4*)d_in[6];
    const float4* xchk4   = (const float4*)d_in[7];
    int4* out4 = (int4*)d_out;

    const int n_points = in_sizes[0] / 2;   // N
    const int npoly = n_points / 8;         // one polygon (8 points) per thread

    const int block = 256;
    const int grid = (npoly + block - 1) / block;   // 8192 blocks, one-shot
    pip_mask_kernel<<<grid, block, 0, stream>>>(points4, s2_4, miny4, maxy4,
                                                xchk4, out4, npoly);
}